// Round 8
// baseline (3500.425 us; speedup 1.0000x reference)
//
#include <hip/hip_runtime.h>

#define DIM 2048
#define LEAK 0.2f

typedef __bf16 bf16x8 __attribute__((ext_vector_type(8)));
typedef float  f32x4  __attribute__((ext_vector_type(4)));
typedef unsigned int u32x4 __attribute__((ext_vector_type(4)));
typedef int    i32x4  __attribute__((ext_vector_type(4)));
typedef int    i32x16 __attribute__((ext_vector_type(16)));

static __device__ __forceinline__ unsigned short f2bf(float f) {
    unsigned int x = __float_as_uint(f);
    return (unsigned short)((x + 0x7fffu + ((x >> 16) & 1u)) >> 16);  // RNE
}
static __device__ __forceinline__ float bf2f(unsigned short h) {
    return __uint_as_float(((unsigned int)h) << 16);
}

static __device__ __forceinline__ void async16(const void* g, void* s) {
    __builtin_amdgcn_global_load_lds(
        (const __attribute__((address_space(1))) void*)g,
        (__attribute__((address_space(3))) void*)s, 16, 0, 0);
}

static __device__ __forceinline__ bf16x8 ld_bf16_frag(const char* p) {
    union { u32x4 u; bf16x8 v; } cv;
    cv.u = *(const u32x4*)p;   // ds_read_b128
    return cv.v;
}

// ---------------- prep kernels ----------------

__global__ __launch_bounds__(256) void split_kernel(
    const float* __restrict__ in,
    unsigned short* __restrict__ hi, unsigned short* __restrict__ lo) {
    int idx = blockIdx.x * 256 + threadIdx.x;
    float4 v = ((const float4*)in)[idx];
    ushort4 h, l;
    h.x = f2bf(v.x); l.x = f2bf(v.x - bf2f(h.x));
    h.y = f2bf(v.y); l.y = f2bf(v.y - bf2f(h.y));
    h.z = f2bf(v.z); l.z = f2bf(v.z - bf2f(h.z));
    h.w = f2bf(v.w); l.w = f2bf(v.w - bf2f(h.w));
    ((ushort4*)hi)[idx] = h;
    ((ushort4*)lo)[idx] = l;
}

__global__ __launch_bounds__(256) void transpose_split(
    const float* __restrict__ in,
    unsigned short* __restrict__ hiT, unsigned short* __restrict__ loT) {
    __shared__ float t[32][33];
    int bx = blockIdx.x, by = blockIdx.y;
    int tx = threadIdx.x & 31, ty4 = (threadIdx.x >> 5) << 2;
#pragma unroll
    for (int i = 0; i < 4; i++)
        t[ty4 + i][tx] = in[(size_t)(by * 32 + ty4 + i) * DIM + bx * 32 + tx];
    __syncthreads();
#pragma unroll
    for (int i = 0; i < 4; i++) {
        float v = t[tx][ty4 + i];
        size_t o = (size_t)(bx * 32 + ty4 + i) * DIM + by * 32 + tx;
        unsigned short h = f2bf(v);
        hiT[o] = h;
        loT[o] = f2bf(v - bf2f(h));
    }
}

__global__ __launch_bounds__(256) void transpose_i8(
    const float* __restrict__ in, signed char* __restrict__ outT) {
    __shared__ float t[32][33];
    int bx = blockIdx.x, by = blockIdx.y;
    int tx = threadIdx.x & 31, ty4 = (threadIdx.x >> 5) << 2;
#pragma unroll
    for (int i = 0; i < 4; i++)
        t[ty4 + i][tx] = in[(size_t)(by * 32 + ty4 + i) * DIM + bx * 32 + tx];
    __syncthreads();
#pragma unroll
    for (int i = 0; i < 4; i++)
        outT[(size_t)(bx * 32 + ty4 + i) * DIM + by * 32 + tx] =
            (signed char)t[tx][ty4 + i];
}

// fp32 state -> row-major planes: h = q>>7, ln = -(q&127)  (q = h*128 - ln)
__global__ __launch_bounds__(256) void quant_splitn(
    const float* __restrict__ in,
    signed char* __restrict__ hi, signed char* __restrict__ ln) {
    int idx = blockIdx.x * 256 + threadIdx.x;
    float4 v = ((const float4*)in)[idx];
    char4 h, l;
    {
        int q = (int)rintf(v.x * 16384.f); q = q > 16383 ? 16383 : (q < -16383 ? -16383 : q);
        h.x = (signed char)(q >> 7); l.x = (signed char)(-(q & 127));
    }
    {
        int q = (int)rintf(v.y * 16384.f); q = q > 16383 ? 16383 : (q < -16383 ? -16383 : q);
        h.y = (signed char)(q >> 7); l.y = (signed char)(-(q & 127));
    }
    {
        int q = (int)rintf(v.z * 16384.f); q = q > 16383 ? 16383 : (q < -16383 ? -16383 : q);
        h.z = (signed char)(q >> 7); l.z = (signed char)(-(q & 127));
    }
    {
        int q = (int)rintf(v.w * 16384.f); q = q > 16383 ? 16383 : (q < -16383 ? -16383 : q);
        h.w = (signed char)(q >> 7); l.w = (signed char)(-(q & 127));
    }
    ((char4*)hi)[idx] = h;
    ((char4*)ln)[idx] = l;
}

// ---------------- bf16 dual-A GEMM (drive), tile 64x128, dbuf (R3, proven) ----------------
template <int MODE>
__global__ __launch_bounds__(256) void gemm_bf16(
    const unsigned short* __restrict__ Ahi,
    const unsigned short* __restrict__ Alo,
    const unsigned short* __restrict__ BT,
    const float* __restrict__ Cin,
    const float* __restrict__ bias,
    float* __restrict__ Cout) {
    __shared__ alignas(16) char sA[2][16384];
    __shared__ alignas(16) char sB[2][16384];

    const int bid = blockIdx.x;
    const int xcd = bid & 7, slot = bid >> 3;
    const int tm = ((xcd >> 1) << 3) + (slot >> 3);
    const int tn = ((xcd & 1) << 3) + (slot & 7);
    const int row0 = tm << 6, col0 = tn << 7;

    const int tid = threadIdx.x;
    const int lane = tid & 63;
    const int quad = lane >> 4, l16 = lane & 15;
    const int wave = tid >> 6;
    const int wm = wave >> 1, wn = wave & 1;

    const unsigned short* a_src[4]; int a_dst[4];
    const unsigned short* b_src[4]; int b_dst[4];
#pragma unroll
    for (int i = 0; i < 4; i++) {
        int s = tid + 256 * i;
        {
            int r = s >> 4, g = (s >> 3) & 1, c = (s & 7) ^ (r & 7);
            a_src[i] = (g ? Alo : Ahi) + (size_t)(row0 + r) * DIM + c * 8;
            a_dst[i] = s * 16;
        }
        {
            int r = s >> 3, c = (s & 7) ^ (r & 7);
            b_src[i] = BT + (size_t)(col0 + r) * DIM + c * 8;
            b_dst[i] = s * 16;
        }
    }

    f32x4 acc[2][4] = {};

    auto stage = [&](int p, int k0) {
#pragma unroll
        for (int i = 0; i < 4; i++) {
            async16(a_src[i] + k0, sA[p] + a_dst[i]);
            async16(b_src[i] + k0, sB[p] + b_dst[i]);
        }
    };

    stage(0, 0);
    __syncthreads();
    for (int it = 0; it < 32; it++) {
        const int p = it & 1;
        if (it + 1 < 32) stage(1 - p, (it + 1) * 64);
#pragma unroll
        for (int kk = 0; kk < 2; kk++) {
            bf16x8 ah[2], al[2], bv[4];
#pragma unroll
            for (int i = 0; i < 2; i++) {
                const int r = (wm << 5) + (i << 4) + l16;
                const int cs = ((kk << 2) + quad) ^ (r & 7);
                ah[i] = ld_bf16_frag(sA[p] + ((r << 4) + cs) * 16);
                al[i] = ld_bf16_frag(sA[p] + ((r << 4) + 8 + cs) * 16);
            }
#pragma unroll
            for (int j = 0; j < 4; j++) {
                const int r = (wn << 6) + (j << 4) + l16;
                const int cs = ((kk << 2) + quad) ^ (r & 7);
                bv[j] = ld_bf16_frag(sB[p] + ((r << 3) + cs) * 16);
            }
#pragma unroll
            for (int i = 0; i < 2; i++)
#pragma unroll
                for (int j = 0; j < 4; j++) {
                    acc[i][j] = __builtin_amdgcn_mfma_f32_16x16x32_bf16(ah[i], bv[j], acc[i][j], 0, 0, 0);
                    acc[i][j] = __builtin_amdgcn_mfma_f32_16x16x32_bf16(al[i], bv[j], acc[i][j], 0, 0, 0);
                }
        }
        __syncthreads();
    }

#pragma unroll
    for (int i = 0; i < 2; i++) {
        const int rb = row0 + (wm << 5) + (i << 4) + (quad << 2);
#pragma unroll
        for (int j = 0; j < 4; j++) {
            const int c = col0 + (wn << 6) + (j << 4) + l16;
#pragma unroll
            for (int g = 0; g < 4; g++) {
                const size_t idx = (size_t)(rb + g) * DIM + c;
                if (MODE == 0) Cout[idx] = acc[i][j][g];
                else           Cout[idx] = Cin[idx] + acc[i][j][g] + bias[c];
            }
        }
    }
}

// ---------------- i8 step v8: 1-wave blocks, barrier-free, 32x32x32 MFMA ----------------
// Block = 1 wave, tile 64x64, grid 1024 (4 independent blocks/CU). No
// __syncthreads anywhere: dbuf ordered by explicit s_waitcnt vmcnt(12)
// (wait prev buffer's 12 staging loads; keep this iter's 12 in flight).
// All operands through LDS (R4/R5/R7: compiler serializes direct loads).
// acc = -q.B exactly: mfma(h, B<<7) + mfma(ln, B)  [R7-proven trick].
__global__ __launch_bounds__(64) void step_v8(
    const signed char* __restrict__ Sh,    // state hi, row-major
    const signed char* __restrict__ Sln,   // state -(lo), row-major
    const signed char* __restrict__ BT,    // adjacency^T, row-major [n][k]
    const float* __restrict__ drive,
    float* __restrict__ out,
    signed char* __restrict__ Oh,
    signed char* __restrict__ Oln,
    int write_f32) {
    __shared__ alignas(16) signed char sA[2][8192];  // 64 rows x 128B (h 0-3 | ln 4-7), XOR-swz
    __shared__ alignas(16) signed char sB[2][4096];  // 64 rows x 64B, XOR-swz

    const int bid = blockIdx.x;
    const int xcd = bid & 7, slot = bid >> 3;        // m-stripe per XCD (write locality)
    const int tm = (xcd << 2) + (slot >> 5);         // 0..31
    const int tn = slot & 31;                         // 0..31
    const int row0 = tm << 6, col0 = tn << 6;

    const int L = threadIdx.x;                        // 0..63
    const int half = L >> 5, l32 = L & 31;

    // staging descriptors (src XOR-swizzled so dst = chunk*16 is lane-ordered)
    const signed char* a_src[8]; int a_dst[8];
#pragma unroll
    for (int i = 0; i < 8; i++) {
        int d = L + 64 * i;                           // 0..511
        int r = d >> 3, c8 = d & 7, g = c8 >> 2, cs = c8 & 3;
        a_src[i] = (g ? Sln : Sh) + (size_t)(row0 + r) * DIM + ((cs ^ (r & 3)) << 4);
        a_dst[i] = d * 16;
    }
    const signed char* b_src[4]; int b_dst[4];
#pragma unroll
    for (int i = 0; i < 4; i++) {
        int d = L + 64 * i;                           // 0..255
        int r = d >> 2, cs = d & 3;
        b_src[i] = BT + (size_t)(col0 + r) * DIM + ((cs ^ (r & 3)) << 4);
        b_dst[i] = d * 16;
    }

    i32x16 acc[2][2] = {};                            // [mb][nb], constant-indexed

    auto stage = [&](int p, int kb) {
#pragma unroll
        for (int i = 0; i < 8; i++) async16(a_src[i] + kb, sA[p] + a_dst[i]);
#pragma unroll
        for (int i = 0; i < 4; i++) async16(b_src[i] + kb, sB[p] + b_dst[i]);
    };

    stage(0, 0);

#pragma unroll 1
    for (int it = 0; it < 32; it++) {
        const int p = it & 1;
        if (it < 31) {
            stage(1 - p, (it + 1) * 64);
            __builtin_amdgcn_s_waitcnt(3964);   // vmcnt(12): prev buffer landed
        } else {
            __builtin_amdgcn_s_waitcnt(3952);   // vmcnt(0): final buffer
        }
        __builtin_amdgcn_sched_barrier(0);
#pragma unroll
        for (int ss = 0; ss < 2; ss++) {              // two K=32 sub-slabs
            i32x4 bv[2], bs[2], ah[2], al[2];
#pragma unroll
            for (int nb = 0; nb < 2; nb++) {
                const int r = (nb << 5) + l32;
                const int c = ((ss << 1) + half) ^ (r & 3);
                bv[nb] = *(const i32x4*)(sB[p] + ((r << 2) + c) * 16);
                bs[nb] = (i32x4)(((u32x4)bv[nb]) << 7);   // bytes 0/1 -> 0/-128
            }
#pragma unroll
            for (int mb = 0; mb < 2; mb++) {
                const int r = (mb << 5) + l32;
                const int c = ((ss << 1) + half) ^ (r & 3);
                ah[mb] = *(const i32x4*)(sA[p] + ((r << 3) + c) * 16);
                al[mb] = *(const i32x4*)(sA[p] + ((r << 3) + 4 + c) * 16);
            }
#pragma unroll
            for (int mb = 0; mb < 2; mb++)
#pragma unroll
                for (int nb = 0; nb < 2; nb++) {
                    acc[mb][nb] = __builtin_amdgcn_mfma_i32_32x32x32_i8(ah[mb], bs[nb], acc[mb][nb], 0, 0, 0);
                    acc[mb][nb] = __builtin_amdgcn_mfma_i32_32x32x32_i8(al[mb], bv[nb], acc[mb][nb], 0, 0, 0);
                }
        }
        __builtin_amdgcn_sched_barrier(0);   // keep next stage below the MFMAs (WAR)
    }

    // epilogue. 32x32 C/D: col = lane&31, row = (reg&3) + 8*(reg>>2) + 4*(lane>>5)
#pragma unroll
    for (int mb = 0; mb < 2; mb++)
#pragma unroll
        for (int nb = 0; nb < 2; nb++) {
            const int c = col0 + (nb << 5) + l32;
#pragma unroll
            for (int j = 0; j < 16; j++) {
                const int r = row0 + (mb << 5) + (j & 3) + ((j >> 2) << 3) + (half << 2);
                const size_t idx = (size_t)r * DIM + c;
                int prod = -acc[mb][nb][j];                    // exact: 16384*(s@A)
                float y = drive[idx] + (float)prod * (1.0f / 16384.0f);
                int soldq = ((int)Sh[idx] << 7) - (int)Sln[idx];
                float sold = (float)soldq * (1.0f / 16384.0f);
                float e = __expf(2.0f * y);
                float th = 1.0f - 2.0f / (e + 1.0f);
                float s = (1.0f - LEAK) * sold + LEAK * th;
                if (write_f32) out[idx] = s;
                int q = (int)rintf(s * 16384.f);
                q = q > 16383 ? 16383 : (q < -16383 ? -16383 : q);
                Oh[idx]  = (signed char)(q >> 7);
                Oln[idx] = (signed char)(-(q & 127));
            }
        }
}

extern "C" void kernel_launch(void* const* d_in, const int* in_sizes, int n_in,
                              void* d_out, int out_size, void* d_ws, size_t ws_size,
                              hipStream_t stream) {
    const float* x    = (const float*)d_in[0];
    const float* wgt  = (const float*)d_in[1];
    const float* adj  = (const float*)d_in[2];
    const float* bias = (const float*)d_in[3];
    const float* st0  = (const float*)d_in[4];
    float* out = (float*)d_out;

    const size_t NE = (size_t)DIM * DIM;
    // ws (52 MB): adjT(4) | drive(16) | bufA(8) bufB(8) bufC(8) bufD(8)
    // State planes (row-major, 4MB each) alias bufC/bufD after GEMMs retire.
    signed char* adjT = (signed char*)d_ws;
    float* drive = (float*)(adjT + NE);
    unsigned short* bufA = (unsigned short*)(drive + NE);
    unsigned short* bufB = bufA + NE;
    unsigned short* bufC = bufB + NE;
    unsigned short* bufD = bufC + NE;
    signed char* S1h = (signed char*)bufC;
    signed char* S1l = S1h + NE;
    signed char* S2h = (signed char*)bufD;
    signed char* S2l = S2h + NE;

    dim3 blk(256);
    transpose_split<<<dim3(64, 64), blk, 0, stream>>>(wgt, bufC, bufD);
    split_kernel<<<dim3(4096), blk, 0, stream>>>(x, bufA, bufB);
    transpose_i8<<<dim3(64, 64), blk, 0, stream>>>(adj, adjT);

    gemm_bf16<0><<<dim3(512), blk, 0, stream>>>(bufA, bufB, bufC, (const float*)0,
                                                (const float*)0, drive);
    gemm_bf16<1><<<dim3(512), blk, 0, stream>>>(bufA, bufB, bufD, drive, bias, drive);

    // state0 -> row-major (h, -l) planes (aliases bufC; GEMMs done in stream order)
    quant_splitn<<<dim3(4096), blk, 0, stream>>>(st0, S1h, S1l);

    signed char* hi = S1h; signed char* li = S1l;
    signed char* ho = S2h; signed char* lo = S2l;
    for (int t = 0; t < 64; t++) {
        step_v8<<<dim3(1024), dim3(64), 0, stream>>>(hi, li, adjT, drive, out,
                                                     ho, lo, (t == 63) ? 1 : 0);
        signed char* th = hi; hi = ho; ho = th;
        signed char* tl = li; li = lo; lo = tl;
    }
}